// Round 4
// baseline (331.440 us; speedup 1.0000x reference)
//
#include <hip/hip_runtime.h>
#include <math.h>

// Problem constants (compile-time fixed)
#define NB   2
#define LQ   13294
#define NROWS (NB*LQ)      // 26588
#define CDIM 256

typedef unsigned short u16;
typedef unsigned int   u32;
typedef short bf16x8 __attribute__((ext_vector_type(8)));
typedef float f32x4  __attribute__((ext_vector_type(4)));

struct alignas(8) U16x4 { u16 x, y, z, w; };

__device__ __forceinline__ u16 f2bf(float f) {   // round-to-nearest-even
    u32 u = __builtin_bit_cast(u32, f);
    u += 0x7FFFu + ((u >> 16) & 1u);
    return (u16)(u >> 16);
}

// Weights -> one bf16 region: [Wv 65536][Woff 65536][Wa 32768][Wo 65536]
// (Woff++Wa contiguous = the 384-row fused-B). Also concat boff++ba bias.
__global__ __launch_bounds__(256)
void prep_weights(const float* __restrict__ Wv, const float* __restrict__ Woff,
                  const float* __restrict__ Wa, const float* __restrict__ Wo,
                  const float* __restrict__ boff, const float* __restrict__ ba,
                  u16* __restrict__ dst, float* __restrict__ biascat) {
    int i = blockIdx.x * 256 + threadIdx.x;
    float v;
    if      (i <  65536) v = Wv[i];
    else if (i < 131072) v = Woff[i - 65536];
    else if (i < 163840) v = Wa[i - 131072];
    else                 v = Wo[i - 163840];
    dst[i] = f2bf(v);
    if (blockIdx.x == 0) {
        int t = threadIdx.x;
        if (t < 256) biascat[t] = boff[t];
        else ;
        if (t < 128) biascat[256 + t] = ba[t];
    }
}

// Register-resident skinny-K GEMM: C[r][c] = sum_k A[r][k]*B[c][k] + bias[c].
// K = 256 fixed. Each wave owns 16 rows, full K in registers (8 bf16x8 frags).
// Block = 4 waves = 64 rows; blockIdx.x picks a 128-col slab (8 col-tiles),
// processed as 4 pairs with 2 independent MFMA chains. No LDS, no barriers.
// SPLIT: cols >= 256 go to C1 (ld 128) — for the fused off+logits GEMM.
template<bool ABF16, bool SPLIT>
__global__ __launch_bounds__(256)
void gemm_reg(const void* __restrict__ Av, const u16* __restrict__ B,
              const float* __restrict__ bias, float* __restrict__ C0,
              float* __restrict__ C1, int M) {
    const int tid  = threadIdx.x;
    const int wave = tid >> 6;
    const int lane = tid & 63;
    const int ln16 = lane & 15;
    const int kq   = lane >> 4;                 // 0..3
    const int rowt = blockIdx.y * 64 + wave * 16;   // tile row base
    const int row  = rowt + ln16;
    const int rcl  = min(row, M - 1);
    const int col0 = blockIdx.x * 128;

    // A fragments: frag kt holds k in [kt*32, kt*32+32); lane k-offset kq*8
    bf16x8 a[8];
    if (ABF16) {
        const u16* Ap = (const u16*)Av + (size_t)rcl * 256 + kq * 8;
        #pragma unroll
        for (int kt = 0; kt < 8; ++kt)
            a[kt] = *(const bf16x8*)(Ap + kt * 32);
    } else {
        const float* Ap = (const float*)Av + (size_t)rcl * 256 + kq * 8;
        #pragma unroll
        for (int kt = 0; kt < 8; ++kt) {
            float4 lo = *(const float4*)(Ap + kt * 32);
            float4 hi = *(const float4*)(Ap + kt * 32 + 4);
            union { u16 h[8]; bf16x8 v; } u;
            u.h[0] = f2bf(lo.x); u.h[1] = f2bf(lo.y);
            u.h[2] = f2bf(lo.z); u.h[3] = f2bf(lo.w);
            u.h[4] = f2bf(hi.x); u.h[5] = f2bf(hi.y);
            u.h[6] = f2bf(hi.z); u.h[7] = f2bf(hi.w);
            a[kt] = u.v;
        }
    }

    const u16* Bbase = B + (size_t)col0 * 256 + kq * 8;
    #pragma unroll
    for (int cp = 0; cp < 4; ++cp) {            // 4 pairs of 16-col tiles
        const u16* b0p = Bbase + (size_t)(cp * 32 + ln16) * 256;
        const u16* b1p = b0p + 16 * 256;
        bf16x8 b0[8], b1[8];
        #pragma unroll
        for (int kt = 0; kt < 8; ++kt) {
            b0[kt] = *(const bf16x8*)(b0p + kt * 32);
            b1[kt] = *(const bf16x8*)(b1p + kt * 32);
        }
        f32x4 ac0 = {}, ac1 = {};
        #pragma unroll
        for (int kt = 0; kt < 8; ++kt) {
            ac0 = __builtin_amdgcn_mfma_f32_16x16x32_bf16(a[kt], b0[kt], ac0, 0, 0, 0);
            ac1 = __builtin_amdgcn_mfma_f32_16x16x32_bf16(a[kt], b1[kt], ac1, 0, 0, 0);
        }
        // C/D layout: col = lane&15 (B index), row = kq*4 + reg (A index)
        #pragma unroll
        for (int h = 0; h < 2; ++h) {
            f32x4 ac = h ? ac1 : ac0;
            int gc = col0 + cp * 32 + h * 16 + ln16;
            float bj = bias[gc];
            #pragma unroll
            for (int r = 0; r < 4; ++r) {
                int gr = rowt + kq * 4 + r;
                if (gr < M) {
                    if (SPLIT && gc >= 256)
                        C1[(size_t)gr * 128 + (gc - 256)] = ac[r] + bj;
                    else
                        C0[(size_t)gr * 256 + gc] = ac[r] + bj;
                }
            }
        }
    }
}

// 4 queries per 256-thread block; 8 lanes (float4 channels) per (q,head).
__global__ __launch_bounds__(256)
void msda_sample(const float* __restrict__ value,    // (NB*LQ, 256) fp32
                 const float* __restrict__ refpts,   // (NB*LQ, 4, 2)
                 const float* __restrict__ off,      // (NB*LQ, 256) fp32
                 const float* __restrict__ logits,   // (NB*LQ, 128) fp32
                 u16* __restrict__ tmp) {            // (NB*LQ, 256) bf16
    constexpr int Hs[4] = {100, 50, 25, 13};
    constexpr int Ws[4] = {100, 50, 25, 13};
    constexpr int st[4] = {0, 10000, 12500, 13125};

    const int t  = threadIdx.x;
    const int qi = t >> 6;
    const int m  = (t >> 3) & 7;
    const int e  = t & 7;
    const int q  = blockIdx.x * 4 + qi;
    const int n  = q / LQ;

    const float* lg = logits + q * 128 + m * 16;
    float w[16];
    float mx = -1e30f;
    #pragma unroll
    for (int i = 0; i < 16; ++i) { w[i] = lg[i]; mx = fmaxf(mx, w[i]); }
    float s = 0.f;
    #pragma unroll
    for (int i = 0; i < 16; ++i) { w[i] = expf(w[i] - mx); s += w[i]; }
    const float inv = 1.f / s;

    const float* offq  = off + q * 256 + m * 32;
    const float* refq  = refpts + q * 8;
    const float* vbase = value + (size_t)(n * LQ) * 256 + m * 32 + e * 4;

    float ax = 0.f, ay = 0.f, az = 0.f, aw_ = 0.f;
    #pragma unroll
    for (int l = 0; l < 4; ++l) {
        const int H = Hs[l], W = Ws[l];
        const float* vl = vbase + (size_t)st[l] * 256;
        const float rx = refq[l * 2 + 0];
        const float ry = refq[l * 2 + 1];
        #pragma unroll
        for (int p = 0; p < 4; ++p) {
            const float ox = offq[l * 8 + p * 2 + 0];
            const float oy = offq[l * 8 + p * 2 + 1];
            const float locx = rx + ox / (float)W;
            const float locy = ry + oy / (float)H;
            const float grx = 2.f * locx - 1.f;
            const float gry = 2.f * locy - 1.f;
            const float gx = ((grx + 1.f) * (float)W - 1.f) * 0.5f;
            const float gy = ((gry + 1.f) * (float)H - 1.f) * 0.5f;
            const float x0f = floorf(gx), y0f = floorf(gy);
            const float fx = gx - x0f, fy = gy - y0f;
            const int x0 = (int)x0f, y0 = (int)y0f;
            const int x1 = x0 + 1, y1 = y0 + 1;

            const int cx0 = min(max(x0, 0), W - 1);
            const int cx1 = min(max(x1, 0), W - 1);
            const int cy0 = min(max(y0, 0), H - 1);
            const int cy1 = min(max(y1, 0), H - 1);
            const bool vx0 = (x0 >= 0) & (x0 < W);
            const bool vx1 = (x1 >= 0) & (x1 < W);
            const bool vy0 = (y0 >= 0) & (y0 < H);
            const bool vy1 = (y1 >= 0) & (y1 < H);

            float4 c00 = *(const float4*)&vl[(size_t)(cy0 * W + cx0) * 256];
            float4 c01 = *(const float4*)&vl[(size_t)(cy0 * W + cx1) * 256];
            float4 c10 = *(const float4*)&vl[(size_t)(cy1 * W + cx0) * 256];
            float4 c11 = *(const float4*)&vl[(size_t)(cy1 * W + cx1) * 256];

            const float aw = w[l * 4 + p] * inv;
            float w00 = (vy0 & vx0) ? aw * (1.f - fy) * (1.f - fx) : 0.f;
            float w01 = (vy0 & vx1) ? aw * (1.f - fy) * fx         : 0.f;
            float w10 = (vy1 & vx0) ? aw * fy * (1.f - fx)         : 0.f;
            float w11 = (vy1 & vx1) ? aw * fy * fx                 : 0.f;

            ax  += w00 * c00.x + w01 * c01.x + w10 * c10.x + w11 * c11.x;
            ay  += w00 * c00.y + w01 * c01.y + w10 * c10.y + w11 * c11.y;
            az  += w00 * c00.z + w01 * c01.z + w10 * c10.z + w11 * c11.z;
            aw_ += w00 * c00.w + w01 * c01.w + w10 * c10.w + w11 * c11.w;
        }
    }
    U16x4 o{f2bf(ax), f2bf(ay), f2bf(az), f2bf(aw_)};
    *(U16x4*)&tmp[(size_t)q * 256 + m * 32 + e * 4] = o;
}

extern "C" void kernel_launch(void* const* d_in, const int* in_sizes, int n_in,
                              void* d_out, int out_size, void* d_ws, size_t ws_size,
                              hipStream_t stream) {
    const float* query  = (const float*)d_in[0];
    const float* refpts = (const float*)d_in[1];
    const float* inflat = (const float*)d_in[2];
    const float* Wv   = (const float*)d_in[5];
    const float* bv   = (const float*)d_in[6];
    const float* Woff = (const float*)d_in[7];
    const float* boff = (const float*)d_in[8];
    const float* Wa   = (const float*)d_in[9];
    const float* ba   = (const float*)d_in[10];
    const float* Wo   = (const float*)d_in[11];
    const float* bo   = (const float*)d_in[12];
    float* out = (float*)d_out;

    // workspace layout
    char* ws = (char*)d_ws;
    float* value = (float*)ws;                                   // 27.2 MB fp32
    float* offb  = (float*)(ws + (size_t)NROWS * 256 * 4);       // 27.2 MB fp32
    float* logit = (float*)(ws + 2 * (size_t)NROWS * 256 * 4);   // 13.6 MB fp32
    u16*   tmp   = (u16*)(ws + 2 * (size_t)NROWS * 256 * 4
                             + (size_t)NROWS * 128 * 4);         // 13.6 MB bf16
    u16*   wb    = (u16*)((char*)tmp + (size_t)NROWS * 256 * 2);
    float* bcat  = (float*)((char*)wb + 229376 * 2);

    dim3 blk(256);
    hipLaunchKernelGGL(prep_weights, dim3(896), blk, 0, stream,
                       Wv, Woff, Wa, Wo, boff, ba, wb, bcat);

    // value = inflat @ Wv^T + bv
    gemm_reg<false, false><<<dim3(2, 416), blk, 0, stream>>>(
        inflat, wb, bv, value, nullptr, NROWS);
    // [offb | logit] = query @ [Woff;Wa]^T + [boff;ba]
    gemm_reg<false, true><<<dim3(3, 416), blk, 0, stream>>>(
        query, wb + 65536, bcat, offb, logit, NROWS);

    hipLaunchKernelGGL(msda_sample, dim3(NROWS / 4), blk, 0, stream,
                       value, refpts, offb, logit, tmp);

    // out = tmp @ Wo^T + bo
    gemm_reg<true, false><<<dim3(2, 416), blk, 0, stream>>>(
        tmp, wb + 163840, bo, out, nullptr, NROWS);
}

// Round 5
// 292.337 us; speedup vs baseline: 1.1338x; 1.1338x over previous
//
#include <hip/hip_runtime.h>
#include <math.h>

// Problem constants (compile-time fixed)
#define NB   2
#define LQ   13294
#define NROWS (NB*LQ)      // 26588
#define CDIM 256

typedef unsigned short u16;
typedef unsigned int   u32;
typedef short bf16x8 __attribute__((ext_vector_type(8)));
typedef float f32x4  __attribute__((ext_vector_type(4)));

struct alignas(8) U16x4 { u16 x, y, z, w; };

__device__ __forceinline__ u16 f2bf(float f) {   // round-to-nearest-even
    u32 u = __builtin_bit_cast(u32, f);
    u += 0x7FFFu + ((u >> 16) & 1u);
    return (u16)(u >> 16);
}

// fp32 -> bf16, 4 elements/thread
__global__ __launch_bounds__(256)
void cvt_bf16(const float4* __restrict__ in, u16* __restrict__ out) {
    int i = blockIdx.x * 256 + threadIdx.x;
    float4 v = in[i];
    U16x4 o{f2bf(v.x), f2bf(v.y), f2bf(v.z), f2bf(v.w)};
    *(U16x4*)&out[(size_t)i * 4] = o;
}

// Weights -> one bf16 region: [Wv 65536][Woff 65536][Wa 32768][Wo 65536]
// (Woff++Wa contiguous = the 384-row fused B). Also bcat = boff++ba (384).
__global__ __launch_bounds__(256)
void prep_weights(const float* __restrict__ Wv, const float* __restrict__ Woff,
                  const float* __restrict__ Wa, const float* __restrict__ Wo,
                  const float* __restrict__ boff, const float* __restrict__ ba,
                  u16* __restrict__ dst, float* __restrict__ biascat) {
    int i = blockIdx.x * 256 + threadIdx.x;
    float v;
    if      (i <  65536) v = Wv[i];
    else if (i < 131072) v = Woff[i - 65536];
    else if (i < 163840) v = Wa[i - 131072];
    else                 v = Wo[i - 163840];
    dst[i] = f2bf(v);
    if (blockIdx.x == 0) {
        int t = threadIdx.x;
        biascat[t] = boff[t];          // t in [0,256)
        if (t < 128) biascat[256 + t] = ba[t];
    }
}

// Persistent-B skinny-K GEMM: C[r][c] = sum_k A[r][k]*B[c][k] + bias[c].
// K = 256. Block = 4 waves, 128(M) x 128(N) tile. B-slab (128 C-cols x 256 k,
// bf16, 64 KB) staged into LDS ONCE; each wave holds its 64-row A strip fully
// in registers (a[4][8]); single __syncthreads; K-loop has no staging, 4:1
// MFMA:ds_read. SPLIT: cols >= 256 go to C1 (ld 128) for fused off|logits.
template<bool SPLIT>
__global__ __launch_bounds__(256, 2)
void gemm_persist(const u16* __restrict__ A, const u16* __restrict__ B,
                  const float* __restrict__ bias, float* __restrict__ C0,
                  float* __restrict__ C1, int M) {
    __shared__ u16 Bs[128 * 256];      // 64 KB, [c][k] k-contiguous
    const int tid  = threadIdx.x;
    const int wave = tid >> 6;
    const int lane = tid & 63;
    const int ln16 = lane & 15;
    const int kq   = lane >> 4;            // 0..3
    const int col0 = blockIdx.x * 128;
    const int row0 = blockIdx.y * 128;
    const int wr   = (wave >> 1) * 64;     // wave row offset in tile
    const int wc   = (wave & 1) * 64;      // wave col offset in tile

    // stage B slab: 4096 16B chunks, coalesced reads, ds_write_b128
    #pragma unroll
    for (int it = 0; it < 16; ++it) {
        int g  = it * 256 + tid;           // chunk id
        int c  = g >> 5;                   // C-col within slab
        int ch = g & 31;                   // 16B chunk within row
        float4 v = *(const float4*)(B + (size_t)(col0 + c) * 256 + ch * 8);
        *(float4*)&Bs[c * 256 + ch * 8] = v;
    }

    // A fragments: 4 row-tiles x full K in registers
    bf16x8 a[4][8];
    #pragma unroll
    for (int i = 0; i < 4; ++i) {
        int gr = min(row0 + wr + i * 16 + ln16, M - 1);
        const u16* Ap = A + (size_t)gr * 256 + kq * 8;
        #pragma unroll
        for (int kt = 0; kt < 8; ++kt)
            a[i][kt] = *(const bf16x8*)(Ap + kt * 32);
    }
    __syncthreads();

    f32x4 acc[4][4] = {};
    #pragma unroll
    for (int kt = 0; kt < 8; ++kt) {
        bf16x8 b[4];
        #pragma unroll
        for (int j = 0; j < 4; ++j)
            b[j] = *(const bf16x8*)&Bs[(wc + j * 16 + ln16) * 256 + kt * 32 + kq * 8];
        #pragma unroll
        for (int i = 0; i < 4; ++i)
            #pragma unroll
            for (int j = 0; j < 4; ++j)
                acc[i][j] = __builtin_amdgcn_mfma_f32_16x16x32_bf16(
                    a[i][kt], b[j], acc[i][j], 0, 0, 0);
    }

    // C/D layout (verified R3): col = lane&15, row = kq*4 + reg
    #pragma unroll
    for (int j = 0; j < 4; ++j) {
        int gc = col0 + wc + j * 16 + ln16;
        float bj = bias[gc];
        #pragma unroll
        for (int i = 0; i < 4; ++i) {
            int gr0 = row0 + wr + i * 16 + kq * 4;
            #pragma unroll
            for (int r = 0; r < 4; ++r) {
                int gr = gr0 + r;
                if (gr < M) {
                    if (SPLIT && gc >= 256)
                        C1[(size_t)gr * 128 + (gc - 256)] = acc[i][j][r] + bj;
                    else
                        C0[(size_t)gr * 256 + gc] = acc[i][j][r] + bj;
                }
            }
        }
    }
}

// 4 queries per 256-thread block; 8 lanes (float4 channels) per (q,head).
__global__ __launch_bounds__(256)
void msda_sample(const float* __restrict__ value,    // (NB*LQ, 256) fp32
                 const float* __restrict__ refpts,   // (NB*LQ, 4, 2)
                 const float* __restrict__ off,      // (NB*LQ, 256) fp32
                 const float* __restrict__ logits,   // (NB*LQ, 128) fp32
                 u16* __restrict__ tmp) {            // (NB*LQ, 256) bf16
    constexpr int Hs[4] = {100, 50, 25, 13};
    constexpr int Ws[4] = {100, 50, 25, 13};
    constexpr int st[4] = {0, 10000, 12500, 13125};

    const int t  = threadIdx.x;
    const int qi = t >> 6;
    const int m  = (t >> 3) & 7;
    const int e  = t & 7;
    const int q  = blockIdx.x * 4 + qi;
    const int n  = q / LQ;

    const float* lg = logits + q * 128 + m * 16;
    float w[16];
    float mx = -1e30f;
    #pragma unroll
    for (int i = 0; i < 16; ++i) { w[i] = lg[i]; mx = fmaxf(mx, w[i]); }
    float s = 0.f;
    #pragma unroll
    for (int i = 0; i < 16; ++i) { w[i] = expf(w[i] - mx); s += w[i]; }
    const float inv = 1.f / s;

    const float* offq  = off + q * 256 + m * 32;
    const float* refq  = refpts + q * 8;
    const float* vbase = value + (size_t)(n * LQ) * 256 + m * 32 + e * 4;

    float ax = 0.f, ay = 0.f, az = 0.f, aw_ = 0.f;
    #pragma unroll
    for (int l = 0; l < 4; ++l) {
        const int H = Hs[l], W = Ws[l];
        const float* vl = vbase + (size_t)st[l] * 256;
        const float rx = refq[l * 2 + 0];
        const float ry = refq[l * 2 + 1];
        #pragma unroll
        for (int p = 0; p < 4; ++p) {
            const float ox = offq[l * 8 + p * 2 + 0];
            const float oy = offq[l * 8 + p * 2 + 1];
            const float locx = rx + ox / (float)W;
            const float locy = ry + oy / (float)H;
            const float grx = 2.f * locx - 1.f;
            const float gry = 2.f * locy - 1.f;
            const float gx = ((grx + 1.f) * (float)W - 1.f) * 0.5f;
            const float gy = ((gry + 1.f) * (float)H - 1.f) * 0.5f;
            const float x0f = floorf(gx), y0f = floorf(gy);
            const float fx = gx - x0f, fy = gy - y0f;
            const int x0 = (int)x0f, y0 = (int)y0f;
            const int x1 = x0 + 1, y1 = y0 + 1;

            const int cx0 = min(max(x0, 0), W - 1);
            const int cx1 = min(max(x1, 0), W - 1);
            const int cy0 = min(max(y0, 0), H - 1);
            const int cy1 = min(max(y1, 0), H - 1);
            const bool vx0 = (x0 >= 0) & (x0 < W);
            const bool vx1 = (x1 >= 0) & (x1 < W);
            const bool vy0 = (y0 >= 0) & (y0 < H);
            const bool vy1 = (y1 >= 0) & (y1 < H);

            float4 c00 = *(const float4*)&vl[(size_t)(cy0 * W + cx0) * 256];
            float4 c01 = *(const float4*)&vl[(size_t)(cy0 * W + cx1) * 256];
            float4 c10 = *(const float4*)&vl[(size_t)(cy1 * W + cx0) * 256];
            float4 c11 = *(const float4*)&vl[(size_t)(cy1 * W + cx1) * 256];

            const float aw = w[l * 4 + p] * inv;
            float w00 = (vy0 & vx0) ? aw * (1.f - fy) * (1.f - fx) : 0.f;
            float w01 = (vy0 & vx1) ? aw * (1.f - fy) * fx         : 0.f;
            float w10 = (vy1 & vx0) ? aw * fy * (1.f - fx)         : 0.f;
            float w11 = (vy1 & vx1) ? aw * fy * fx                 : 0.f;

            ax  += w00 * c00.x + w01 * c01.x + w10 * c10.x + w11 * c11.x;
            ay  += w00 * c00.y + w01 * c01.y + w10 * c10.y + w11 * c11.y;
            az  += w00 * c00.z + w01 * c01.z + w10 * c10.z + w11 * c11.z;
            aw_ += w00 * c00.w + w01 * c01.w + w10 * c10.w + w11 * c11.w;
        }
    }
    U16x4 o{f2bf(ax), f2bf(ay), f2bf(az), f2bf(aw_)};
    *(U16x4*)&tmp[(size_t)q * 256 + m * 32 + e * 4] = o;
}

extern "C" void kernel_launch(void* const* d_in, const int* in_sizes, int n_in,
                              void* d_out, int out_size, void* d_ws, size_t ws_size,
                              hipStream_t stream) {
    const float* query  = (const float*)d_in[0];
    const float* refpts = (const float*)d_in[1];
    const float* inflat = (const float*)d_in[2];
    const float* Wv   = (const float*)d_in[5];
    const float* bv   = (const float*)d_in[6];
    const float* Woff = (const float*)d_in[7];
    const float* boff = (const float*)d_in[8];
    const float* Wa   = (const float*)d_in[9];
    const float* ba   = (const float*)d_in[10];
    const float* Wo   = (const float*)d_in[11];
    const float* bo   = (const float*)d_in[12];
    float* out = (float*)d_out;

    // workspace layout (82.1 MB); qb reused as tmp, ib reused as logit
    char* ws = (char*)d_ws;
    constexpr size_t SZ16 = (size_t)NROWS * 256 * 2;            // 13,613,056
    constexpr size_t SZ32 = (size_t)NROWS * 256 * 4;            // 27,226,112
    u16*   qb    = (u16*)(ws);                                  // bf16 query; later tmp
    u16*   ib    = (u16*)(ws + SZ16);                           // bf16 input; later logit
    float* value = (float*)(ws + 2 * SZ16);                     // fp32
    float* offb  = (float*)(ws + 2 * SZ16 + SZ32);              // fp32
    u16*   wb    = (u16*)(ws + 2 * SZ16 + 2 * SZ32);            // bf16 weights
    float* bcat  = (float*)(ws + 2 * SZ16 + 2 * SZ32 + 229376 * 2);
    float* logit = (float*)ib;                                  // fp32 NROWS*128
    u16*   tmp   = qb;                                          // bf16 NROWS*256

    dim3 blk(256);
    hipLaunchKernelGGL(cvt_bf16, dim3(6647), blk, 0, stream, (const float4*)query,  qb);
    hipLaunchKernelGGL(cvt_bf16, dim3(6647), blk, 0, stream, (const float4*)inflat, ib);
    hipLaunchKernelGGL(prep_weights, dim3(896), blk, 0, stream,
                       Wv, Woff, Wa, Wo, boff, ba, wb, bcat);

    // value = inflat @ Wv^T + bv
    gemm_persist<false><<<dim3(2, 208), blk, 0, stream>>>(
        ib, wb, bv, value, nullptr, NROWS);
    // [offb | logit] = query @ [Woff;Wa]^T + [boff;ba]
    gemm_persist<true><<<dim3(3, 208), blk, 0, stream>>>(
        qb, wb + 65536, bcat, offb, logit, NROWS);

    hipLaunchKernelGGL(msda_sample, dim3(NROWS / 4), blk, 0, stream,
                       value, refpts, offb, logit, tmp);

    // out = tmp @ Wo^T + bo
    gemm_persist<false><<<dim3(2, 208), blk, 0, stream>>>(
        tmp, wb + 163840, bo, out, nullptr, NROWS);
}